// Round 8
// baseline (585.243 us; speedup 1.0000x reference)
//
#include <hip/hip_runtime.h>

typedef __bf16 bf16x8 __attribute__((ext_vector_type(8)));
typedef _Float16 f16x8 __attribute__((ext_vector_type(8)));
typedef float floatx4 __attribute__((ext_vector_type(4)));

__device__ __forceinline__ unsigned short f2bf(float f) {
  unsigned int u = __float_as_uint(f);
  u += 0x7FFFu + ((u >> 16) & 1u);  // RNE
  return (unsigned short)(u >> 16);
}
__device__ __forceinline__ unsigned short f2h(float f) {
  _Float16 h = (_Float16)f;
  return __builtin_bit_cast(unsigned short, h);
}
template <bool F16>
__device__ __forceinline__ unsigned short f2x(float f) {
  return F16 ? f2h(f) : f2bf(f);
}
__device__ __forceinline__ unsigned short f2rt(float f, bool f16) {
  return f16 ? f2h(f) : f2bf(f);
}

// async global->LDS, 16B per lane. LDS dest = wave-uniform base + lane*16.
__device__ __forceinline__ void g2l16(const void* g, void* l) {
  __builtin_amdgcn_global_load_lds(
      (const __attribute__((address_space(1))) void*)g,
      (__attribute__((address_space(3))) void*)l, 16, 0, 0);
}

// ---------------------------------------------------------------------------
// C[M,N] = A[M,K] * B[N,K]^T. 128x128x64 tile, 4 waves, 4x4 of 16x16x32 MFMA.
// == r6 champion structure (440.7 us) == (r7's BK=32 regressed: only 4 16B
// slots/row -> XOR can't spread a 16-lane group past 4 bank-quads, conflicts
// returned at 1.26e7. BK=64/8-slot swizzle is the verified conflict-free one.)
//  * T4 counted-vmcnt: dbuf LDS, stage t+1 before compute t, raw s_barrier,
//    vmcnt(8) steady gate, vmcnt(0) only at tail.
//  * T1 XCD chunking; T2 XOR swizzle (slot s of row r holds global s^(r&7);
//    g2l16 dest linear, source pre-swizzled, ds_read same XOR — rule #21).
//  * T5 setprio(1) around the MFMA cluster.
// Swapped mfma(b,a): lane (qr,lr), frag (i,j), reg r holds
//   C[m0+wr+i*16+lr][n0+wc+j*16+qr*4+r]  -> vectorized epilogue stores.
// Operand-role rule (verified by rounds 3-7 passing): lane&15 indexes the
// SECOND operand's row, qr*4+reg the FIRST's. So for the V-projection we use
// UNswapped mfma(a,b): lane holds C[t=m0+wr+i*16+qr*4+r][v=n0+wc+j*16+lr]
// -> 4 consecutive t per lane -> direct V^T store (kills the vtrans pass).
// MODE 0: C = relu(acc + bias[col]) -> fp16 if OUTF16 else bf16
// MODE 1: C = exp(acc - 60) -> bf16, lrow[z*2048+row] += rowsum (atomics)
// MODE 2: C = acc / lrow[z*2048+row] -> fp32; if C1 && z>=4 write to
//         C1 + (z-4)*sC instead (bounce for d_out aliasing)
// AF32:   A fp32 in global, converted during staging (legacy sync loop).
// PROJ3:  fused projections; z in {0,1,2} selects weight (sB), bias
//         (bcat+z*1024), output {Cv,C1,C2}. z==2 (V): unswapped MFMA +
//         transposed bf16 store into C2 as Vt[b][v][t] (b=row>>11).
// ---------------------------------------------------------------------------
template <int MODE, bool AF32, bool INF16, bool OUTF16, bool PROJ3>
__global__ __launch_bounds__(256) void gemm_bt(
    const void* __restrict__ Av, int lda, long sA,
    const unsigned short* __restrict__ B, int ldb, long sB,
    void* __restrict__ Cv, int ldc, long sC,
    int K, const float* __restrict__ bias, float* __restrict__ lrow,
    void* __restrict__ C1, void* __restrict__ C2) {
  __shared__ unsigned short As[2][128 * 64];
  __shared__ unsigned short Bs[2][128 * 64];
  const int tid = threadIdx.x;
  const int wave = tid >> 6, lane = tid & 63;
  const int z = blockIdx.z;
  const unsigned short* A16 = (const unsigned short*)Av + (size_t)z * sA;
  const float* A32 = (const float*)Av + (size_t)z * sA;
  B += (size_t)z * sB;

  // PROJ3 per-z selection
  void* Cz = Cv;
  const float* biasz = bias;
  bool outf16 = OUTF16;
  const bool zV = PROJ3 && (z == 2);  // V-projection: unswapped + V^T store
  if (PROJ3) {
    biasz = bias + z * 1024;
    if (z == 1) Cz = C1;
    else if (z == 2) { Cz = C2; outf16 = false; }
  }

  // T1: XCD-aware bijective chunking of the (x,y) plane.
  int bx = blockIdx.x, by = blockIdx.y;
  {
    const int nwg = gridDim.x * gridDim.y;
    if ((nwg & 7) == 0) {
      int flat = by * gridDim.x + bx;
      flat = (flat & 7) * (nwg >> 3) + (flat >> 3);
      bx = flat % gridDim.x;
      by = flat / gridDim.x;
    }
  }
  const int m0 = by * 128, n0 = bx * 128;
  const int wr = (wave >> 1) * 64;
  const int wc = (wave & 1) * 64;
  const int qr = lane >> 4, lr = lane & 15;
  floatx4 acc[4][4] = {};

  // stage K-tile t (non-AF32): 4+4 = 8 global_load_lds, 16B/lane.
  auto stageAB = [&](int t, int buf) {
    const int k0 = t << 6;
#pragma unroll
    for (int it = 0; it < 4; ++it) {
      const int base = it * 256 + wave * 64;  // wave-uniform LDS dest
      const int idx = base + lane;
      const int row = idx >> 3;
      const int gs = (idx & 7) ^ (row & 7);  // inverse-swizzled global slot
      g2l16(A16 + (size_t)(m0 + row) * lda + k0 + gs * 8, &As[buf][base * 8]);
    }
#pragma unroll
    for (int it = 0; it < 4; ++it) {
      const int base = it * 256 + wave * 64;
      const int idx = base + lane;
      const int row = idx >> 3;
      const int gs = (idx & 7) ^ (row & 7);
      g2l16(B + (size_t)(n0 + row) * ldb + k0 + gs * 8, &Bs[buf][base * 8]);
    }
  };

  auto computeT = [&](int buf) {
#pragma unroll
    for (int kk = 0; kk < 64; kk += 32) {
      const int slot = (kk >> 3) + qr;  // wanted global 16B slot (0..7)
      if (INF16) {
        f16x8 af[4], bf[4];
#pragma unroll
        for (int i = 0; i < 4; ++i) {
          const int ra = wr + i * 16 + lr;
          af[i] = *(const f16x8*)&As[buf][ra * 64 + ((slot ^ (ra & 7)) * 8)];
        }
#pragma unroll
        for (int j = 0; j < 4; ++j) {
          const int rb = wc + j * 16 + lr;
          bf[j] = *(const f16x8*)&Bs[buf][rb * 64 + ((slot ^ (rb & 7)) * 8)];
        }
        __builtin_amdgcn_s_setprio(1);
        if (zV) {
#pragma unroll
          for (int i = 0; i < 4; ++i)
#pragma unroll
            for (int j = 0; j < 4; ++j)
              acc[i][j] = __builtin_amdgcn_mfma_f32_16x16x32_f16(
                  af[i], bf[j], acc[i][j], 0, 0, 0);
        } else {
#pragma unroll
          for (int i = 0; i < 4; ++i)
#pragma unroll
            for (int j = 0; j < 4; ++j)
              acc[i][j] = __builtin_amdgcn_mfma_f32_16x16x32_f16(
                  bf[j], af[i], acc[i][j], 0, 0, 0);
        }
        __builtin_amdgcn_s_setprio(0);
      } else {
        bf16x8 af[4], bf[4];
#pragma unroll
        for (int i = 0; i < 4; ++i) {
          const int ra = wr + i * 16 + lr;
          af[i] = *(const bf16x8*)&As[buf][ra * 64 + ((slot ^ (ra & 7)) * 8)];
        }
#pragma unroll
        for (int j = 0; j < 4; ++j) {
          const int rb = wc + j * 16 + lr;
          bf[j] = *(const bf16x8*)&Bs[buf][rb * 64 + ((slot ^ (rb & 7)) * 8)];
        }
        __builtin_amdgcn_s_setprio(1);
#pragma unroll
        for (int i = 0; i < 4; ++i)
#pragma unroll
          for (int j = 0; j < 4; ++j)
            acc[i][j] = __builtin_amdgcn_mfma_f32_16x16x32_bf16(
                bf[j], af[i], acc[i][j], 0, 0, 0);
        __builtin_amdgcn_s_setprio(0);
      }
    }
  };

  if (!AF32) {
    // T4 pipeline: tile t+1 loads stay in flight across the barrier; only
    // counted waits (vmcnt(8)) in the main loop, vmcnt(0) only at the tail.
    const int nk = K >> 6;
    stageAB(0, 0);
    for (int t = 0; t < nk; ++t) {
      const int cur = t & 1;
      if (t + 1 < nk) {
        stageAB(t + 1, cur ^ 1);
        asm volatile("s_waitcnt vmcnt(8)" ::: "memory");  // tile t landed
      } else {
        asm volatile("s_waitcnt vmcnt(0)" ::: "memory");
      }
      __builtin_amdgcn_sched_barrier(0);
      __builtin_amdgcn_s_barrier();  // all waves' tile-t loads landed
      __builtin_amdgcn_sched_barrier(0);
      computeT(cur);
      __builtin_amdgcn_sched_barrier(0);
      __builtin_amdgcn_s_barrier();  // all waves done reading buf cur
      __builtin_amdgcn_sched_barrier(0);
    }
  } else {
    // legacy synchronous loop (ds_write staging; __syncthreads drains all)
    for (int k0 = 0; k0 < K; k0 += 64) {
      __syncthreads();
#pragma unroll
      for (int it = 0; it < 8; ++it) {
        const int idx = it * 256 + tid;  // 0..2047 float4-chunks
        const int row = idx >> 4, c4 = idx & 15;
        float4 v =
            *(const float4*)(A32 + (size_t)(m0 + row) * lda + k0 + c4 * 4);
        const int soff = (((c4 >> 1) ^ (row & 7)) * 2 + (c4 & 1)) * 4;
        *(ushort4*)&As[0][row * 64 + soff] =
            make_ushort4(f2x<INF16>(v.x), f2x<INF16>(v.y), f2x<INF16>(v.z),
                         f2x<INF16>(v.w));
      }
#pragma unroll
      for (int it = 0; it < 4; ++it) {
        const int base = it * 256 + wave * 64;
        const int idx = base + lane;
        const int row = idx >> 3;
        const int gs = (idx & 7) ^ (row & 7);
        g2l16(B + (size_t)(n0 + row) * ldb + k0 + gs * 8, &Bs[0][base * 8]);
      }
      __syncthreads();
      computeT(0);
    }
  }

  // -------- Epilogue --------
  if (zV) {
    // Unswapped layout: lane holds C[t=m0+wr+i*16+qr*4+r][v=n0+wc+j*16+lr].
    // Store V^T: Vt[b][v][t], b = t_global>>11, ldt = 2048.
    unsigned short* Vt = (unsigned short*)Cz;
#pragma unroll
    for (int i = 0; i < 4; ++i) {
      const int trow0 = m0 + wr + i * 16 + qr * 4;  // 4-run stays in batch
      const size_t vb = (size_t)(trow0 >> 11) * (1024ull * 2048);
      const int tt = trow0 & 2047;
#pragma unroll
      for (int j = 0; j < 4; ++j) {
        const int vcol = n0 + wc + j * 16 + lr;
        const float bvv = biasz[vcol];
        float v0 = fmaxf(acc[i][j][0] + bvv, 0.0f);
        float v1 = fmaxf(acc[i][j][1] + bvv, 0.0f);
        float v2 = fmaxf(acc[i][j][2] + bvv, 0.0f);
        float v3 = fmaxf(acc[i][j][3] + bvv, 0.0f);
        *(ushort4*)&Vt[vb + (size_t)vcol * 2048 + tt] =
            make_ushort4(f2bf(v0), f2bf(v1), f2bf(v2), f2bf(v3));
      }
    }
    return;
  }

  // Swapped layout: row = m0+wr+i*16+lr ; col = n0+wc+j*16+qr*4+r
  float* Cf = (float*)Cz + (size_t)z * sC;
  if (MODE == 2 && C1 != nullptr && z >= 4)
    Cf = (float*)C1 + (size_t)(z - 4) * sC;  // bounce upper batches
  unsigned short* Cb = (unsigned short*)Cz + (size_t)z * sC;
#pragma unroll
  for (int i = 0; i < 4; ++i) {
    const int row = m0 + wr + i * 16 + lr;
    float rowsum = 0.0f;
    float invl = 1.0f;
    if (MODE == 2) invl = 1.0f / lrow[(size_t)z * 2048 + row];
#pragma unroll
    for (int j = 0; j < 4; ++j) {
      const int col0 = n0 + wc + j * 16 + qr * 4;
      if (MODE == 0) {
        float4 bj = *(const float4*)(biasz + col0);
        float v0 = fmaxf(acc[i][j][0] + bj.x, 0.0f);
        float v1 = fmaxf(acc[i][j][1] + bj.y, 0.0f);
        float v2 = fmaxf(acc[i][j][2] + bj.z, 0.0f);
        float v3 = fmaxf(acc[i][j][3] + bj.w, 0.0f);
        *(ushort4*)&Cb[(size_t)row * ldc + col0] =
            make_ushort4(f2rt(v0, outf16), f2rt(v1, outf16),
                         f2rt(v2, outf16), f2rt(v3, outf16));
      } else if (MODE == 1) {
        float e0 = __expf(acc[i][j][0] - 60.0f);
        float e1 = __expf(acc[i][j][1] - 60.0f);
        float e2 = __expf(acc[i][j][2] - 60.0f);
        float e3 = __expf(acc[i][j][3] - 60.0f);
        *(ushort4*)&Cb[(size_t)row * ldc + col0] =
            make_ushort4(f2bf(e0), f2bf(e1), f2bf(e2), f2bf(e3));
        rowsum += (e0 + e1) + (e2 + e3);
      } else {
        *(float4*)&Cf[(size_t)row * ldc + col0] =
            make_float4(acc[i][j][0] * invl, acc[i][j][1] * invl,
                        acc[i][j][2] * invl, acc[i][j][3] * invl);
      }
    }
    if (MODE == 1) {
      // lanes lr, lr+16, lr+32, lr+48 hold the same row's partial sums
      rowsum += __shfl_xor(rowsum, 16);
      rowsum += __shfl_xor(rowsum, 32);
      if (lane < 16)
        atomicAdd(&lrow[(size_t)z * 2048 + row], rowsum);
    }
  }
}

// ===========================================================================
// prep: single fused dispatch: cvt16 + 3x wtrans + zero_l + bias concat.
//   [0, 8192)      : X fp32 -> Xh fp16 (2048 elems/block)
//   [8192, 8960)   : wtrans for W{q,k,v} -> Wt fp16 (256 blocks each)
//   [8960, 9024)   : zero l[16384]
//   [9024]         : bcat[3072] = {bq, bk, bv}
// ===========================================================================
__global__ __launch_bounds__(256) void prep(
    const float* __restrict__ X, unsigned short* __restrict__ Xh,
    const float* __restrict__ Wq, const float* __restrict__ Wk,
    const float* __restrict__ Wv, unsigned short* __restrict__ Wqt,
    unsigned short* __restrict__ Wkt, unsigned short* __restrict__ Wvt,
    const float* __restrict__ bq, const float* __restrict__ bk,
    const float* __restrict__ bv, float* __restrict__ bcat,
    float* __restrict__ l) {
  __shared__ unsigned short t[64][68];
  const int bid = blockIdx.x;
  const int tid = threadIdx.x;
  if (bid < 8192) {
    const int i = (bid * 256 + tid) * 8;
    float4 a = *(const float4*)(X + i);
    float4 b = *(const float4*)(X + i + 4);
    *(ushort4*)(Xh + i) = make_ushort4(f2h(a.x), f2h(a.y), f2h(a.z), f2h(a.w));
    *(ushort4*)(Xh + i + 4) =
        make_ushort4(f2h(b.x), f2h(b.y), f2h(b.z), f2h(b.w));
  } else if (bid < 8960) {
    const int w = (bid - 8192) >> 8;
    const int lb = (bid - 8192) & 255;
    const float* W = (w == 0) ? Wq : (w == 1) ? Wk : Wv;
    unsigned short* Wt = (w == 0) ? Wqt : (w == 1) ? Wkt : Wvt;
    const int n0 = (lb & 15) * 64, k0 = (lb >> 4) * 64;
#pragma unroll
    for (int it = 0; it < 4; ++it) {
      const int idx = it * 256 + tid;
      const int kr = idx >> 4, nq = idx & 15;
      float4 v = *(const float4*)&W[(size_t)(k0 + kr) * 1024 + n0 + nq * 4];
      t[kr][nq * 4 + 0] = f2h(v.x);
      t[kr][nq * 4 + 1] = f2h(v.y);
      t[kr][nq * 4 + 2] = f2h(v.z);
      t[kr][nq * 4 + 3] = f2h(v.w);
    }
    __syncthreads();
#pragma unroll
    for (int it = 0; it < 4; ++it) {
      const int idx = it * 256 + tid;
      const int nr = idx >> 4, kq = idx & 15;
      *(ushort4*)&Wt[(size_t)(n0 + nr) * 1024 + k0 + kq * 4] =
          make_ushort4(t[kq * 4 + 0][nr], t[kq * 4 + 1][nr],
                       t[kq * 4 + 2][nr], t[kq * 4 + 3][nr]);
    }
  } else if (bid < 9024) {
    const int i = (bid - 8960) * 256 + tid;
    l[i] = 0.0f;
  } else {
#pragma unroll
    for (int it = 0; it < 12; ++it) {
      const int idx = it * 256 + tid;
      bcat[idx] = (idx < 1024) ? bq[idx]
                  : (idx < 2048) ? bk[idx - 1024] : bv[idx - 2048];
    }
  }
}

// V[b][t][v] 16-bit -> Vt[b][v][t] 16-bit (SMALL path only)
__global__ __launch_bounds__(256) void vtrans(const unsigned short* __restrict__ V,
                                              unsigned short* __restrict__ Vt) {
  __shared__ unsigned short t[64][68];
  const int tid = threadIdx.x;
  const int v0 = blockIdx.x * 64, t0 = blockIdx.y * 64;
  const int b = blockIdx.z;
  const unsigned short* Vb = V + (size_t)b * 2048 * 1024;
  unsigned short* Vtb = Vt + (size_t)b * 1024 * 2048;
#pragma unroll
  for (int it = 0; it < 4; ++it) {
    const int idx = it * 256 + tid;
    const int tr = idx >> 4, vq = idx & 15;
    ushort4 u = *(const ushort4*)&Vb[(size_t)(t0 + tr) * 1024 + v0 + vq * 4];
    t[tr][vq * 4 + 0] = u.x;
    t[tr][vq * 4 + 1] = u.y;
    t[tr][vq * 4 + 2] = u.z;
    t[tr][vq * 4 + 3] = u.w;
  }
  __syncthreads();
#pragma unroll
  for (int it = 0; it < 4; ++it) {
    const int idx = it * 256 + tid;
    const int vr = idx >> 4, tq = idx & 15;
    *(ushort4*)&Vtb[(size_t)(v0 + vr) * 2048 + t0 + tq * 4] =
        make_ushort4(t[tq * 4 + 0][vr], t[tq * 4 + 1][vr],
                     t[tq * 4 + 2][vr], t[tq * 4 + 3][vr]);
  }
}

// flat float4 copy (n floats, multiple of 1024*256*... grid-sized exactly)
__global__ __launch_bounds__(256) void copyflat(const float* __restrict__ src,
                                                float* __restrict__ dst) {
  const size_t i = ((size_t)blockIdx.x * 256 + threadIdx.x) * 4;
  *(float4*)(dst + i) = *(const float4*)(src + i);
}

// Copy half-output T[b][0..1023][1024] fp32 -> out[b][roff+0..1023][1024].
__global__ __launch_bounds__(256) void copy_half(const float* __restrict__ T,
                                                 float* __restrict__ out,
                                                 int roff) {
  const size_t i = ((size_t)blockIdx.x * 256 + threadIdx.x) * 4;
  const size_t b = i >> 20;
  const size_t rem = i & 1048575;
  float4 v = *(const float4*)(T + i);
  *(float4*)(out + b * 2097152 + (size_t)roff * 1024 + rem) = v;
}

__global__ void diag_ws(float* __restrict__ out, float mb) { out[0] = mb; }

extern "C" void kernel_launch(void* const* d_in, const int* in_sizes, int n_in,
                              void* d_out, int out_size, void* d_ws, size_t ws_size,
                              hipStream_t stream) {
  const float* X = (const float*)d_in[0];
  const float* Wq = (const float*)d_in[1];
  const float* bq = (const float*)d_in[2];
  const float* Wk = (const float*)d_in[3];
  const float* bk = (const float*)d_in[4];
  const float* Wv = (const float*)d_in[5];
  const float* bv = (const float*)d_in[6];
  float* out = (float*)d_out;
  char* ws = (char*)d_ws;
  const size_t MiB = 1ull << 20;

  // ---- BIG layout (ws >= ~134 MB) ----
  const size_t B_WQT = 0, B_WKT = 2 * MiB, B_WVT = 4 * MiB;
  const size_t B_Q = 6 * MiB;     // 32 MiB fp16 (Q; later: PV bounce for z>=4)
  const size_t B_K = 38 * MiB;    // 32 MiB fp16
  const size_t B_E = 70 * MiB;    // 64 MiB bf16
  const size_t B_L = 134 * MiB;   // 64 KiB l + 16 KiB bcat
  const size_t NEEDED_BIG = B_L + 65536 + 16384;

  // ---- SMALL layout: E overlays d_out, bounce GEMM3 ----
  const size_t S_WQT = 0, S_WKT = 2 * MiB, S_WVT = 4 * MiB;
  const size_t S_Q = 6 * MiB, S_K = 38 * MiB, S_L = 70 * MiB;
  const size_t NEEDED_SMALL = S_L + 65536 + 16384;

  if (ws_size >= NEEDED_BIG) {
    unsigned short* Wqt = (unsigned short*)(ws + B_WQT);
    unsigned short* Wkt = (unsigned short*)(ws + B_WKT);
    unsigned short* Wvt = (unsigned short*)(ws + B_WVT);
    unsigned short* Q   = (unsigned short*)(ws + B_Q);
    unsigned short* Kb  = (unsigned short*)(ws + B_K);
    unsigned short* E   = (unsigned short*)(ws + B_E);
    float* l            = (float*)(ws + B_L);
    float* bcat         = (float*)(ws + B_L + 65536);
    unsigned short* Xh = (unsigned short*)d_out;
    unsigned short* Vt = (unsigned short*)d_out + 16384ull * 1024;  // [b][v][t]

    prep<<<9025, 256, 0, stream>>>(X, Xh, Wq, Wk, Wv, Wqt, Wkt, Wvt,
                                   bq, bk, bv, bcat, l);

    // fused Q/K/V projections: Q,K fp16 -> ws; V -> V^T bf16 direct into
    // d_out upper half (unswapped-mfma transposed store; no vtrans pass).
    gemm_bt<0, false, true, true, true><<<dim3(8, 128, 3), 256, 0, stream>>>(
        Xh, 1024, 0, Wqt, 1024, 1048576, Q, 1024, 0, 1024, bcat, nullptr,
        Kb, Vt);

    // E[b] = exp(Q K^T - 60) bf16 into ws; l rowsums
    gemm_bt<1, false, true, false, false><<<dim3(16, 16, 8), 256, 0, stream>>>(
        Q, 1024, 2048L * 1024, Kb, 1024, 2048L * 1024,
        E, 2048, 2048L * 2048, 1024, nullptr, l, nullptr, nullptr);

    // out = (E * Vt^T)/l. Batches 0-3 -> d_out[0,32MiB) (Xh dead);
    // batches 4-7 bounce to Q's region (dead) to avoid clobbering Vt.
    float* T = (float*)Q;
    gemm_bt<2, false, false, false, false><<<dim3(8, 16, 8), 256, 0, stream>>>(
        E, 2048, 2048L * 2048, Vt, 2048, 1024L * 2048,
        out, 1024, 2048L * 1024, 2048, nullptr, l, T, nullptr);

    // copy bounced batches 4-7 (32 MiB) into d_out upper half (Vt dead now)
    copyflat<<<8192, 256, 0, stream>>>(T, out + 4ull * 2048 * 1024);
    return;
  }

  if (ws_size < NEEDED_SMALL) {
    diag_ws<<<1, 1, 0, stream>>>(out, (float)(ws_size >> 20));
    return;
  }

  // ---------------- SMALL path (r6 structure) ----------------
  unsigned short* Wqt = (unsigned short*)(ws + S_WQT);
  unsigned short* Wkt = (unsigned short*)(ws + S_WKT);
  unsigned short* Wvt = (unsigned short*)(ws + S_WVT);
  unsigned short* Q   = (unsigned short*)(ws + S_Q);
  unsigned short* Kb  = (unsigned short*)(ws + S_K);
  float* l            = (float*)(ws + S_L);
  float* bcat         = (float*)(ws + S_L + 65536);
  unsigned short* Xh = (unsigned short*)d_out;
  unsigned short* E  = (unsigned short*)d_out;

  prep<<<9025, 256, 0, stream>>>(X, Xh, Wq, Wk, Wv, Wqt, Wkt, Wvt,
                                 bq, bk, bv, bcat, l);

  // fused Q/K projections (z=2); V comes later from fp32 X (E overlays Xh)
  gemm_bt<0, false, true, true, true><<<dim3(8, 128, 2), 256, 0, stream>>>(
      Xh, 1024, 0, Wqt, 1024, 1048576, Q, 1024, 0, 1024, bcat, nullptr,
      Kb, nullptr);

  gemm_bt<1, false, true, false, false><<<dim3(16, 16, 8), 256, 0, stream>>>(
      Q, 1024, 2048L * 1024, Kb, 1024, 2048L * 1024,
      E, 2048, 2048L * 2048, 1024, nullptr, l, nullptr, nullptr);

  // V-proj from fp32 X (E overlays Xh in d_out): legacy AF32 path
  gemm_bt<0, true, true, false, false><<<dim3(8, 128, 1), 256, 0, stream>>>(
      X, 1024, 0, Wvt, 1024, 0, Kb, 1024, 0, 1024, bv, nullptr,
      nullptr, nullptr);

  vtrans<<<dim3(16, 32, 8), 256, 0, stream>>>(Kb, Q);

  float* T = (float*)Kb;
  gemm_bt<2, false, false, false, false><<<dim3(8, 8, 8), 256, 0, stream>>>(
      E, 2048, 2048L * 2048, Q, 2048, 1024L * 2048,
      T, 1024, 1024L * 1024, 2048, nullptr, l, nullptr, nullptr);
  copy_half<<<8192, 256, 0, stream>>>(T, out, 0);
  gemm_bt<2, false, false, false, false><<<dim3(8, 8, 8), 256, 0, stream>>>(
      E + 1024L * 2048, 2048, 2048L * 2048, Q, 2048, 1024L * 2048,
      T, 1024, 1024L * 1024, 2048, nullptr, l + 1024, nullptr, nullptr);
  copy_half<<<8192, 256, 0, stream>>>(T, out, 1024);
}

// Round 9
// 418.138 us; speedup vs baseline: 1.3996x; 1.3996x over previous
//
#include <hip/hip_runtime.h>

typedef __bf16 bf16x8 __attribute__((ext_vector_type(8)));
typedef _Float16 f16x8 __attribute__((ext_vector_type(8)));
typedef float floatx4 __attribute__((ext_vector_type(4)));

__device__ __forceinline__ unsigned short f2bf(float f) {
  unsigned int u = __float_as_uint(f);
  u += 0x7FFFu + ((u >> 16) & 1u);  // RNE
  return (unsigned short)(u >> 16);
}
__device__ __forceinline__ unsigned short f2h(float f) {
  _Float16 h = (_Float16)f;
  return __builtin_bit_cast(unsigned short, h);
}
template <bool F16>
__device__ __forceinline__ unsigned short f2x(float f) {
  return F16 ? f2h(f) : f2bf(f);
}
__device__ __forceinline__ unsigned short f2rt(float f, bool f16) {
  return f16 ? f2h(f) : f2bf(f);
}

// async global->LDS, 16B per lane. LDS dest = wave-uniform base + lane*16.
__device__ __forceinline__ void g2l16(const void* g, void* l) {
  __builtin_amdgcn_global_load_lds(
      (const __attribute__((address_space(1))) void*)g,
      (__attribute__((address_space(3))) void*)l, 16, 0, 0);
}

// ---------------------------------------------------------------------------
// C[M,N] = A[M,K] * B[N,K]^T. 128x128x64 tile, 4 waves, 4x4 of 16x16x32 MFMA.
// == r6 champion structure (440.7 us), codegen-identical for ZV=false ==
// (r8 lesson: a RUNTIME operand-order branch in the inner loop ballooned VGPR
// 88->136, occupancy 21->11.5%, proj3 141->305 us. ZV is now a TEMPLATE param
// -> separate instantiation, clean regalloc.)
//  * T4 counted-vmcnt: dbuf LDS, stage t+1 before compute t, raw s_barrier,
//    vmcnt(8) steady gate, vmcnt(0) only at tail.
//  * T1 XCD chunking; T2 XOR swizzle (slot s of row r holds global s^(r&7);
//    g2l16 dest linear, source pre-swizzled, ds_read same XOR — rule #21).
// Swapped mfma(b,a): lane (qr,lr), frag (i,j), reg r holds
//   C[m0+wr+i*16+lr][n0+wc+j*16+qr*4+r]  -> vectorized epilogue stores.
// ZV (V-projection, HW-verified in r8): UNswapped mfma(a,b) -> lane holds
//   C[t=m0+wr+i*16+qr*4+r][v=n0+wc+j*16+lr]; epilogue stores V^T directly:
//   Vt[b][v][t], b=t>>11, ld=2048 (relu+bias applied, bf16).
// MODE 0: C = relu(acc + bias[col]) -> fp16 if OUTF16 else bf16
// MODE 1: C = exp(acc - 60) -> bf16, lrow[z*2048+row] += rowsum (atomics)
// MODE 2: C = acc / lrow[z*2048+row] -> fp32
// AF32:   A fp32 in global, converted during staging (legacy sync loop).
// PROJ3:  fused projections; z selects weight (sB), bias (bcat+z*1024),
//         output {Cv,C1,C2}[z]; fp16 out for z<2, bf16 for z==2.
// ---------------------------------------------------------------------------
template <int MODE, bool AF32, bool INF16, bool OUTF16, bool PROJ3, bool ZV>
__global__ __launch_bounds__(256) void gemm_bt(
    const void* __restrict__ Av, int lda, long sA,
    const unsigned short* __restrict__ B, int ldb, long sB,
    void* __restrict__ Cv, int ldc, long sC,
    int K, const float* __restrict__ bias, float* __restrict__ lrow,
    void* __restrict__ C1, void* __restrict__ C2) {
  __shared__ unsigned short As[2][128 * 64];
  __shared__ unsigned short Bs[2][128 * 64];
  const int tid = threadIdx.x;
  const int wave = tid >> 6, lane = tid & 63;
  const int z = blockIdx.z;
  const unsigned short* A16 = (const unsigned short*)Av + (size_t)z * sA;
  const float* A32 = (const float*)Av + (size_t)z * sA;
  B += (size_t)z * sB;

  // PROJ3 per-z selection
  void* Cz = Cv;
  const float* biasz = bias;
  bool outf16 = OUTF16;
  if (PROJ3) {
    biasz = bias + z * 1024;
    if (z == 1) Cz = C1;
    else if (z == 2) { Cz = C2; outf16 = false; }
  }

  // T1: XCD-aware bijective chunking of the (x,y) plane.
  int bx = blockIdx.x, by = blockIdx.y;
  {
    const int nwg = gridDim.x * gridDim.y;
    if ((nwg & 7) == 0) {
      int flat = by * gridDim.x + bx;
      flat = (flat & 7) * (nwg >> 3) + (flat >> 3);
      bx = flat % gridDim.x;
      by = flat / gridDim.x;
    }
  }
  const int m0 = by * 128, n0 = bx * 128;
  const int wr = (wave >> 1) * 64;
  const int wc = (wave & 1) * 64;
  const int qr = lane >> 4, lr = lane & 15;
  floatx4 acc[4][4] = {};

  // stage K-tile t (non-AF32): 4+4 = 8 global_load_lds, 16B/lane.
  auto stageAB = [&](int t, int buf) {
    const int k0 = t << 6;
#pragma unroll
    for (int it = 0; it < 4; ++it) {
      const int base = it * 256 + wave * 64;  // wave-uniform LDS dest
      const int idx = base + lane;
      const int row = idx >> 3;
      const int gs = (idx & 7) ^ (row & 7);  // inverse-swizzled global slot
      g2l16(A16 + (size_t)(m0 + row) * lda + k0 + gs * 8, &As[buf][base * 8]);
    }
#pragma unroll
    for (int it = 0; it < 4; ++it) {
      const int base = it * 256 + wave * 64;
      const int idx = base + lane;
      const int row = idx >> 3;
      const int gs = (idx & 7) ^ (row & 7);
      g2l16(B + (size_t)(n0 + row) * ldb + k0 + gs * 8, &Bs[buf][base * 8]);
    }
  };

  auto computeT = [&](int buf) {
#pragma unroll
    for (int kk = 0; kk < 64; kk += 32) {
      const int slot = (kk >> 3) + qr;  // wanted global 16B slot (0..7)
      if (INF16) {
        f16x8 af[4], bf[4];
#pragma unroll
        for (int i = 0; i < 4; ++i) {
          const int ra = wr + i * 16 + lr;
          af[i] = *(const f16x8*)&As[buf][ra * 64 + ((slot ^ (ra & 7)) * 8)];
        }
#pragma unroll
        for (int j = 0; j < 4; ++j) {
          const int rb = wc + j * 16 + lr;
          bf[j] = *(const f16x8*)&Bs[buf][rb * 64 + ((slot ^ (rb & 7)) * 8)];
        }
        if (ZV) {  // compile-time: unswapped (V^T layout)
#pragma unroll
          for (int i = 0; i < 4; ++i)
#pragma unroll
            for (int j = 0; j < 4; ++j)
              acc[i][j] = __builtin_amdgcn_mfma_f32_16x16x32_f16(
                  af[i], bf[j], acc[i][j], 0, 0, 0);
        } else {
#pragma unroll
          for (int i = 0; i < 4; ++i)
#pragma unroll
            for (int j = 0; j < 4; ++j)
              acc[i][j] = __builtin_amdgcn_mfma_f32_16x16x32_f16(
                  bf[j], af[i], acc[i][j], 0, 0, 0);
        }
      } else {
        bf16x8 af[4], bf[4];
#pragma unroll
        for (int i = 0; i < 4; ++i) {
          const int ra = wr + i * 16 + lr;
          af[i] = *(const bf16x8*)&As[buf][ra * 64 + ((slot ^ (ra & 7)) * 8)];
        }
#pragma unroll
        for (int j = 0; j < 4; ++j) {
          const int rb = wc + j * 16 + lr;
          bf[j] = *(const bf16x8*)&Bs[buf][rb * 64 + ((slot ^ (rb & 7)) * 8)];
        }
#pragma unroll
        for (int i = 0; i < 4; ++i)
#pragma unroll
          for (int j = 0; j < 4; ++j)
            acc[i][j] = __builtin_amdgcn_mfma_f32_16x16x32_bf16(
                bf[j], af[i], acc[i][j], 0, 0, 0);
      }
    }
  };

  if (!AF32) {
    // T4 pipeline: tile t+1 loads stay in flight across the barrier; only
    // counted waits (vmcnt(8)) in the main loop, vmcnt(0) only at the tail.
    const int nk = K >> 6;
    stageAB(0, 0);
    for (int t = 0; t < nk; ++t) {
      const int cur = t & 1;
      if (t + 1 < nk) {
        stageAB(t + 1, cur ^ 1);
        asm volatile("s_waitcnt vmcnt(8)" ::: "memory");  // tile t landed
      } else {
        asm volatile("s_waitcnt vmcnt(0)" ::: "memory");
      }
      __builtin_amdgcn_sched_barrier(0);
      __builtin_amdgcn_s_barrier();  // all waves' tile-t loads landed
      __builtin_amdgcn_sched_barrier(0);
      computeT(cur);
      __builtin_amdgcn_sched_barrier(0);
      __builtin_amdgcn_s_barrier();  // all waves done reading buf cur
      __builtin_amdgcn_sched_barrier(0);
    }
  } else {
    // legacy synchronous loop (ds_write staging; __syncthreads drains all)
    for (int k0 = 0; k0 < K; k0 += 64) {
      __syncthreads();
#pragma unroll
      for (int it = 0; it < 8; ++it) {
        const int idx = it * 256 + tid;  // 0..2047 float4-chunks
        const int row = idx >> 4, c4 = idx & 15;
        float4 v =
            *(const float4*)(A32 + (size_t)(m0 + row) * lda + k0 + c4 * 4);
        const int soff = (((c4 >> 1) ^ (row & 7)) * 2 + (c4 & 1)) * 4;
        *(ushort4*)&As[0][row * 64 + soff] =
            make_ushort4(f2x<INF16>(v.x), f2x<INF16>(v.y), f2x<INF16>(v.z),
                         f2x<INF16>(v.w));
      }
#pragma unroll
      for (int it = 0; it < 4; ++it) {
        const int base = it * 256 + wave * 64;
        const int idx = base + lane;
        const int row = idx >> 3;
        const int gs = (idx & 7) ^ (row & 7);
        g2l16(B + (size_t)(n0 + row) * ldb + k0 + gs * 8, &Bs[0][base * 8]);
      }
      __syncthreads();
      computeT(0);
    }
  }

  // -------- Epilogue --------
  if (ZV) {
    // Unswapped layout (HW-verified r8): lane holds
    // C[t=m0+wr+i*16+qr*4+r][v=n0+wc+j*16+lr]. Store Vt[b][v][t], b=t>>11.
    unsigned short* Vt = (unsigned short*)Cz;
#pragma unroll
    for (int i = 0; i < 4; ++i) {
      const int trow0 = m0 + wr + i * 16 + qr * 4;  // 4-run stays in batch
      const size_t vb = (size_t)(trow0 >> 11) * (1024ull * 2048);
      const int tt = trow0 & 2047;
#pragma unroll
      for (int j = 0; j < 4; ++j) {
        const int vcol = n0 + wc + j * 16 + lr;
        const float bvv = biasz[vcol];
        float v0 = fmaxf(acc[i][j][0] + bvv, 0.0f);
        float v1 = fmaxf(acc[i][j][1] + bvv, 0.0f);
        float v2 = fmaxf(acc[i][j][2] + bvv, 0.0f);
        float v3 = fmaxf(acc[i][j][3] + bvv, 0.0f);
        *(ushort4*)&Vt[vb + (size_t)vcol * 2048 + tt] =
            make_ushort4(f2bf(v0), f2bf(v1), f2bf(v2), f2bf(v3));
      }
    }
    return;
  }

  // Swapped layout: row = m0+wr+i*16+lr ; col = n0+wc+j*16+qr*4+r
  float* Cf = (float*)Cz + (size_t)z * sC;
  unsigned short* Cb = (unsigned short*)Cz + (size_t)z * sC;
#pragma unroll
  for (int i = 0; i < 4; ++i) {
    const int row = m0 + wr + i * 16 + lr;
    float rowsum = 0.0f;
    float invl = 1.0f;
    if (MODE == 2) invl = 1.0f / lrow[(size_t)z * 2048 + row];
#pragma unroll
    for (int j = 0; j < 4; ++j) {
      const int col0 = n0 + wc + j * 16 + qr * 4;
      if (MODE == 0) {
        float4 bj = *(const float4*)(biasz + col0);
        float v0 = fmaxf(acc[i][j][0] + bj.x, 0.0f);
        float v1 = fmaxf(acc[i][j][1] + bj.y, 0.0f);
        float v2 = fmaxf(acc[i][j][2] + bj.z, 0.0f);
        float v3 = fmaxf(acc[i][j][3] + bj.w, 0.0f);
        *(ushort4*)&Cb[(size_t)row * ldc + col0] =
            make_ushort4(f2rt(v0, outf16), f2rt(v1, outf16),
                         f2rt(v2, outf16), f2rt(v3, outf16));
      } else if (MODE == 1) {
        float e0 = __expf(acc[i][j][0] - 60.0f);
        float e1 = __expf(acc[i][j][1] - 60.0f);
        float e2 = __expf(acc[i][j][2] - 60.0f);
        float e3 = __expf(acc[i][j][3] - 60.0f);
        *(ushort4*)&Cb[(size_t)row * ldc + col0] =
            make_ushort4(f2bf(e0), f2bf(e1), f2bf(e2), f2bf(e3));
        rowsum += (e0 + e1) + (e2 + e3);
      } else {
        *(float4*)&Cf[(size_t)row * ldc + col0] =
            make_float4(acc[i][j][0] * invl, acc[i][j][1] * invl,
                        acc[i][j][2] * invl, acc[i][j][3] * invl);
      }
    }
    if (MODE == 1) {
      // lanes lr, lr+16, lr+32, lr+48 hold the same row's partial sums
      rowsum += __shfl_xor(rowsum, 16);
      rowsum += __shfl_xor(rowsum, 32);
      if (lane < 16)
        atomicAdd(&lrow[(size_t)z * 2048 + row], rowsum);
    }
  }
}

// ===========================================================================
// prep: single fused dispatch: cvt16 + 3x wtrans + zero_l + bias concat.
//   [0, 8192)      : X fp32 -> Xh fp16 (2048 elems/block)
//   [8192, 8960)   : wtrans for W{q,k,v} -> Wt fp16 (256 blocks each)
//   [8960, 9024)   : zero l[16384]
//   [9024]         : bcat[3072] = {bq, bk, bv}
// ===========================================================================
__global__ __launch_bounds__(256) void prep(
    const float* __restrict__ X, unsigned short* __restrict__ Xh,
    const float* __restrict__ Wq, const float* __restrict__ Wk,
    const float* __restrict__ Wv, unsigned short* __restrict__ Wqt,
    unsigned short* __restrict__ Wkt, unsigned short* __restrict__ Wvt,
    const float* __restrict__ bq, const float* __restrict__ bk,
    const float* __restrict__ bv, float* __restrict__ bcat,
    float* __restrict__ l) {
  __shared__ unsigned short t[64][68];
  const int bid = blockIdx.x;
  const int tid = threadIdx.x;
  if (bid < 8192) {
    const int i = (bid * 256 + tid) * 8;
    float4 a = *(const float4*)(X + i);
    float4 b = *(const float4*)(X + i + 4);
    *(ushort4*)(Xh + i) = make_ushort4(f2h(a.x), f2h(a.y), f2h(a.z), f2h(a.w));
    *(ushort4*)(Xh + i + 4) =
        make_ushort4(f2h(b.x), f2h(b.y), f2h(b.z), f2h(b.w));
  } else if (bid < 8960) {
    const int w = (bid - 8192) >> 8;
    const int lb = (bid - 8192) & 255;
    const float* W = (w == 0) ? Wq : (w == 1) ? Wk : Wv;
    unsigned short* Wt = (w == 0) ? Wqt : (w == 1) ? Wkt : Wvt;
    const int n0 = (lb & 15) * 64, k0 = (lb >> 4) * 64;
#pragma unroll
    for (int it = 0; it < 4; ++it) {
      const int idx = it * 256 + tid;
      const int kr = idx >> 4, nq = idx & 15;
      float4 v = *(const float4*)&W[(size_t)(k0 + kr) * 1024 + n0 + nq * 4];
      t[kr][nq * 4 + 0] = f2h(v.x);
      t[kr][nq * 4 + 1] = f2h(v.y);
      t[kr][nq * 4 + 2] = f2h(v.z);
      t[kr][nq * 4 + 3] = f2h(v.w);
    }
    __syncthreads();
#pragma unroll
    for (int it = 0; it < 4; ++it) {
      const int idx = it * 256 + tid;
      const int nr = idx >> 4, kq = idx & 15;
      *(ushort4*)&Wt[(size_t)(n0 + nr) * 1024 + k0 + kq * 4] =
          make_ushort4(t[kq * 4 + 0][nr], t[kq * 4 + 1][nr],
                       t[kq * 4 + 2][nr], t[kq * 4 + 3][nr]);
    }
  } else if (bid < 9024) {
    const int i = (bid - 8960) * 256 + tid;
    l[i] = 0.0f;
  } else {
#pragma unroll
    for (int it = 0; it < 12; ++it) {
      const int idx = it * 256 + tid;
      bcat[idx] = (idx < 1024) ? bq[idx]
                  : (idx < 2048) ? bk[idx - 1024] : bv[idx - 2048];
    }
  }
}

// V[b][t][v] 16-bit -> Vt[b][v][t] 16-bit (SMALL path only)
__global__ __launch_bounds__(256) void vtrans(const unsigned short* __restrict__ V,
                                              unsigned short* __restrict__ Vt) {
  __shared__ unsigned short t[64][68];
  const int tid = threadIdx.x;
  const int v0 = blockIdx.x * 64, t0 = blockIdx.y * 64;
  const int b = blockIdx.z;
  const unsigned short* Vb = V + (size_t)b * 2048 * 1024;
  unsigned short* Vtb = Vt + (size_t)b * 1024 * 2048;
#pragma unroll
  for (int it = 0; it < 4; ++it) {
    const int idx = it * 256 + tid;
    const int tr = idx >> 4, vq = idx & 15;
    ushort4 u = *(const ushort4*)&Vb[(size_t)(t0 + tr) * 1024 + v0 + vq * 4];
    t[tr][vq * 4 + 0] = u.x;
    t[tr][vq * 4 + 1] = u.y;
    t[tr][vq * 4 + 2] = u.z;
    t[tr][vq * 4 + 3] = u.w;
  }
  __syncthreads();
#pragma unroll
  for (int it = 0; it < 4; ++it) {
    const int idx = it * 256 + tid;
    const int vr = idx >> 4, tq = idx & 15;
    *(ushort4*)&Vtb[(size_t)(v0 + vr) * 2048 + t0 + tq * 4] =
        make_ushort4(t[tq * 4 + 0][vr], t[tq * 4 + 1][vr],
                     t[tq * 4 + 2][vr], t[tq * 4 + 3][vr]);
  }
}

// Copy half-output T[b][0..1023][1024] fp32 -> out[b][roff+0..1023][1024].
__global__ __launch_bounds__(256) void copy_half(const float* __restrict__ T,
                                                 float* __restrict__ out,
                                                 int roff) {
  const size_t i = ((size_t)blockIdx.x * 256 + threadIdx.x) * 4;
  const size_t b = i >> 20;
  const size_t rem = i & 1048575;
  float4 v = *(const float4*)(T + i);
  *(float4*)(out + b * 2097152 + (size_t)roff * 1024 + rem) = v;
}

__global__ void diag_ws(float* __restrict__ out, float mb) { out[0] = mb; }

extern "C" void kernel_launch(void* const* d_in, const int* in_sizes, int n_in,
                              void* d_out, int out_size, void* d_ws, size_t ws_size,
                              hipStream_t stream) {
  const float* X = (const float*)d_in[0];
  const float* Wq = (const float*)d_in[1];
  const float* bq = (const float*)d_in[2];
  const float* Wk = (const float*)d_in[3];
  const float* bk = (const float*)d_in[4];
  const float* Wv = (const float*)d_in[5];
  const float* bv = (const float*)d_in[6];
  float* out = (float*)d_out;
  char* ws = (char*)d_ws;
  const size_t MiB = 1ull << 20;

  // ---- BIG layout (ws >= ~134 MB) ----
  const size_t B_WQT = 0, B_WKT = 2 * MiB, B_WVT = 4 * MiB;
  const size_t B_Q = 6 * MiB;     // 32 MiB fp16 Q; after QK^T: Vt bf16
  const size_t B_K = 38 * MiB;    // 32 MiB fp16
  const size_t B_E = 70 * MiB;    // 64 MiB bf16
  const size_t B_L = 134 * MiB;   // 64 KiB l + 16 KiB bcat
  const size_t NEEDED_BIG = B_L + 65536 + 16384;

  // ---- SMALL layout: E overlays d_out, bounce GEMM3 ----
  const size_t S_WQT = 0, S_WKT = 2 * MiB, S_WVT = 4 * MiB;
  const size_t S_Q = 6 * MiB, S_K = 38 * MiB, S_L = 70 * MiB;
  const size_t NEEDED_SMALL = S_L + 65536 + 16384;

  if (ws_size >= NEEDED_BIG) {
    unsigned short* Wqt = (unsigned short*)(ws + B_WQT);
    unsigned short* Wkt = (unsigned short*)(ws + B_WKT);
    unsigned short* Wvt = (unsigned short*)(ws + B_WVT);
    unsigned short* Q   = (unsigned short*)(ws + B_Q);
    unsigned short* Kb  = (unsigned short*)(ws + B_K);
    unsigned short* E   = (unsigned short*)(ws + B_E);
    float* l            = (float*)(ws + B_L);
    float* bcat         = (float*)(ws + B_L + 65536);
    unsigned short* Xh = (unsigned short*)d_out;  // alive until PV writes out
    unsigned short* Vt = Q;  // V^T reuses Q's region (Q dead after QK^T)

    prep<<<9025, 256, 0, stream>>>(X, Xh, Wq, Wk, Wv, Wqt, Wkt, Wvt,
                                   bq, bk, bv, bcat, l);

    // fused Q/K projections (z=2): Q,K fp16 -> ws
    gemm_bt<0, false, true, true, true, false>
        <<<dim3(8, 128, 2), 256, 0, stream>>>(
        Xh, 1024, 0, Wqt, 1024, 1048576, Q, 1024, 0, 1024, bcat, nullptr,
        Kb, nullptr);

    // E[b] = exp(Q K^T - 60) bf16 into ws; l rowsums
    gemm_bt<1, false, true, false, false, false>
        <<<dim3(16, 16, 8), 256, 0, stream>>>(
        Q, 1024, 2048L * 1024, Kb, 1024, 2048L * 1024,
        E, 2048, 2048L * 2048, 1024, nullptr, l, nullptr, nullptr);

    // V-projection AFTER QK^T: reads Xh (still alive), writes V^T straight
    // into Q's region via the unswapped-MFMA transposed epilogue (no vtrans).
    gemm_bt<0, false, true, false, false, true>
        <<<dim3(8, 128, 1), 256, 0, stream>>>(
        Xh, 1024, 0, Wvt, 1024, 0, Vt, 2048, 0, 1024, bv, nullptr,
        nullptr, nullptr);

    // out = (E * Vt^T)/l straight into d_out (Xh dead now; no aliasing)
    gemm_bt<2, false, false, false, false, false>
        <<<dim3(8, 16, 8), 256, 0, stream>>>(
        E, 2048, 2048L * 2048, Vt, 2048, 1024L * 2048,
        out, 1024, 2048L * 1024, 2048, nullptr, l, nullptr, nullptr);
    return;
  }

  if (ws_size < NEEDED_SMALL) {
    diag_ws<<<1, 1, 0, stream>>>(out, (float)(ws_size >> 20));
    return;
  }

  // ---------------- SMALL path (r6 structure, unchanged) ----------------
  unsigned short* Wqt = (unsigned short*)(ws + S_WQT);
  unsigned short* Wkt = (unsigned short*)(ws + S_WKT);
  unsigned short* Wvt = (unsigned short*)(ws + S_WVT);
  unsigned short* Q   = (unsigned short*)(ws + S_Q);
  unsigned short* Kb  = (unsigned short*)(ws + S_K);
  float* l            = (float*)(ws + S_L);
  float* bcat         = (float*)(ws + S_L + 65536);
  unsigned short* Xh = (unsigned short*)d_out;
  unsigned short* E  = (unsigned short*)d_out;

  prep<<<9025, 256, 0, stream>>>(X, Xh, Wq, Wk, Wv, Wqt, Wkt, Wvt,
                                 bq, bk, bv, bcat, l);

  // fused Q/K projections (z=2); V comes later from fp32 X (E overlays Xh)
  gemm_bt<0, false, true, true, true, false>
      <<<dim3(8, 128, 2), 256, 0, stream>>>(
      Xh, 1024, 0, Wqt, 1024, 1048576, Q, 1024, 0, 1024, bcat, nullptr,
      Kb, nullptr);

  gemm_bt<1, false, true, false, false, false>
      <<<dim3(16, 16, 8), 256, 0, stream>>>(
      Q, 1024, 2048L * 1024, Kb, 1024, 2048L * 1024,
      E, 2048, 2048L * 2048, 1024, nullptr, l, nullptr, nullptr);

  // V-proj from fp32 X (E overlays Xh in d_out): legacy AF32 path
  gemm_bt<0, true, true, false, false, false>
      <<<dim3(8, 128, 1), 256, 0, stream>>>(
      X, 1024, 0, Wvt, 1024, 0, Kb, 1024, 0, 1024, bv, nullptr,
      nullptr, nullptr);

  vtrans<<<dim3(16, 32, 8), 256, 0, stream>>>(Kb, Q);

  float* T = (float*)Kb;
  gemm_bt<2, false, false, false, false, false>
      <<<dim3(8, 8, 8), 256, 0, stream>>>(
      E, 2048, 2048L * 2048, Q, 2048, 1024L * 2048,
      T, 1024, 1024L * 1024, 2048, nullptr, l, nullptr, nullptr);
  copy_half<<<8192, 256, 0, stream>>>(T, out, 0);
  gemm_bt<2, false, false, false, false, false>
      <<<dim3(8, 8, 8), 256, 0, stream>>>(
      E + 1024L * 2048, 2048, 2048L * 2048, Q, 2048, 1024L * 2048,
      T, 1024, 1024L * 1024, 2048, nullptr, l + 1024, nullptr, nullptr);
  copy_half<<<8192, 256, 0, stream>>>(T, out, 1024);
}